// Round 2
// baseline (870.799 us; speedup 1.0000x reference)
//
#include <hip/hip_runtime.h>
#include <hip/hip_cooperative_groups.h>

namespace cg = cooperative_groups;

// HDR+ align fused: 4-level gaussian pyramid + tile block matching + subpixel refine.
// T=16, SR=4, PADD=1, SS=11, SSC=9, WIN=26, SW=0.1, GR=2. Batch NB=4, imgs 512x512.
// Single cooperative kernel, 8 phases separated by grid.sync() — removes the
// ~15us/launch serialization that dominated the 8-kernel version (162us total,
// sum of real pipe work is <20us).

#define TSZ 16
#define SS 11
#define SSC 9
#define WIN 26
#define NB 4

#define NBLK 1024
#define NTHR 256

// Composite 1D tap of (normalized gaussian sigma=1 r=2) followed by avg-pool-2:
// h[u] = 0.5*(gn[u] + gn[u-1]), gn out-of-range -> 0.
__device__ __constant__ float c_h[6] = {
    0.027244342f, 0.149345013f, 0.323410645f,
    0.323410645f, 0.149345013f, 0.027244342f
};

// Fused blur(zero-pad) + 2x2 avg-pool for 8 images (4 src + 4 dst), grid-strided.
template<int Hi, int Wi>
__device__ __forceinline__ void pyr_phase(const float* __restrict__ inS, const float* __restrict__ inD,
                                          float* __restrict__ outS, float* __restrict__ outD,
                                          int gtid, int nthr) {
    constexpr int Ho = Hi / 2, Wo = Wi / 2;
    constexpr int PER = Ho * Wo;
    for (int idx = gtid; idx < 8 * PER; idx += nthr) {
        int z   = idx / PER;            // pow2 -> shift
        int rem = idx & (PER - 1);
        int y   = rem / Wo;             // pow2 -> shift
        int x   = rem & (Wo - 1);
        const float* in = (z < 4) ? (inS + (size_t)z * Hi * Wi) : (inD + (size_t)(z - 4) * Hi * Wi);
        float*      out = (z < 4) ? (outS + (size_t)z * PER)    : (outD + (size_t)(z - 4) * PER);
        int yb = 2 * y - 2, xb = 2 * x - 2;
        float acc = 0.0f;
        #pragma unroll
        for (int u = 0; u < 6; ++u) {
            int yy = yb + u;
            if (yy < 0 || yy >= Hi) continue;   // zero padding
            float ra = 0.0f;
            #pragma unroll
            for (int v = 0; v < 6; ++v) {
                int xx = xb + v;
                if (xx < 0 || xx >= Wi) continue;
                ra = fmaf(c_h[v], in[yy * Wi + xx], ra);
            }
            acc = fmaf(c_h[u], ra, acc);
        }
        out[y * Wo + x] = acc;
    }
}

// One block-matching level; each block loops over its share of tiles.
template<int H, int W, int NTH, int NTW, bool FIRST, bool LAST>
__device__ __forceinline__ void step_phase(const float* __restrict__ srcLvl, const float* __restrict__ dstLvl,
                                           const float* __restrict__ prevOff, float* __restrict__ outOff,
                                           float* __restrict__ outMinDist,
                                           float* win, float* stile, float* dist,
                                           float* initf, int* ioff,
                                           int bid, int nblocks, int t) {
    constexpr int PNTH = NTH / 2, PNTW = NTW / 2;
    constexpr int NT = NTH * NTW;
    for (int tile = bid; tile < NB * NT; tile += nblocks) {
        int b   = tile / NT;            // pow2 -> shift
        int rem = tile & (NT - 1);
        int ty  = rem / NTW;            // pow2 -> shift
        int tx  = rem & (NTW - 1);

        if (t == 0) {
            float dyf = 0.0f, dxf = 0.0f;
            if (!FIRST) {
                int pty = ty >> 1, ptx = tx >> 1;
                const float* p = prevOff + ((size_t)(b * PNTH + pty) * PNTW + ptx) * 2;
                float o0 = 2.0f * p[0], o1 = 2.0f * p[1];
                float iy = (float)(ty * TSZ), ix = (float)(tx * TSZ);
                // _inherit: round(clip(off+i, 0, dim-T) - i), half-to-even like jnp.round
                dyf = rintf(fminf(fmaxf(o0 + iy, 0.0f), (float)(H - TSZ)) - iy);
                dxf = rintf(fminf(fmaxf(o1 + ix, 0.0f), (float)(W - TSZ)) - ix);
            }
            initf[0] = dyf; initf[1] = dxf;
            ioff[0] = (int)dyf; ioff[1] = (int)dxf;
        }
        __syncthreads();

        const float* simg = srcLvl + (size_t)b * H * W;
        const float* dimg = dstLvl + (size_t)b * H * W;
        const int y0 = ty * TSZ + ioff[0] - (SS / 2);
        const int x0 = tx * TSZ + ioff[1] - (SS / 2);

        for (int idx = t; idx < WIN * WIN; idx += NTHR) {
            int r = idx / WIN, c = idx - r * WIN;
            int gy = min(max(y0 + r, 0), H - 1);
            int gx = min(max(x0 + c, 0), W - 1);
            win[idx] = dimg[gy * W + gx];
        }
        for (int idx = t; idx < TSZ * TSZ; idx += NTHR) {
            int i = idx >> 4, j = idx & 15;
            stile[idx] = simg[(ty * TSZ + i) * W + tx * TSZ + j];
        }
        __syncthreads();

        if (t < SS * SS) {
            int dy = t / SS, dx = t - dy * SS;
            float ssd = 0.0f;
            const float* wbase = &win[dy * WIN + dx];
            #pragma unroll 4
            for (int i = 0; i < TSZ; ++i) {
                const float* wr = wbase + i * WIN;
                const float4* sp = (const float4*)&stile[i * TSZ];  // 64B-aligned rows
                #pragma unroll
                for (int q = 0; q < 4; ++q) {
                    float4 s = sp[q];
                    float d0 = wr[4 * q + 0] - s.x;
                    float d1 = wr[4 * q + 1] - s.y;
                    float d2 = wr[4 * q + 2] - s.z;
                    float d3 = wr[4 * q + 3] - s.w;
                    ssd = fmaf(d0, d0, ssd);
                    ssd = fmaf(d1, d1, ssd);
                    ssd = fmaf(d2, d2, ssd);
                    ssd = fmaf(d3, d3, ssd);
                }
            }
            float ay = (float)(dy - 5) * (1.0f / 11.0f);
            float ax = (float)(dx - 5) * (1.0f / 11.0f);
            dist[t] = ssd * (1.0f / 256.0f) + 0.1f * (ay * ay + ax * ax);
        }
        __syncthreads();

        // argmin over central 9x9 (first occurrence in row-major = smallest k on tie)
        float bv = 3e38f; int bk = 1 << 30;
        if (t < 64) {
            int kk = t;
            if (kk < SSC * SSC) {
                int py = kk / SSC, px = kk - (kk / SSC) * SSC;
                bv = dist[(py + 1) * SS + (px + 1)]; bk = kk;
            }
            kk = t + 64;
            if (kk < SSC * SSC) {
                int py = kk / SSC, px = kk - (kk / SSC) * SSC;
                float d = dist[(py + 1) * SS + (px + 1)];
                if (d < bv || (d == bv && kk < bk)) { bv = d; bk = kk; }
            }
            #pragma unroll
            for (int s = 32; s > 0; s >>= 1) {
                float ov = __shfl_down(bv, s);
                int   ok = __shfl_down(bk, s);
                if (ov < bv || (ov == bv && ok < bk)) { bv = ov; bk = ok; }
            }
        }
        if (t == 0) {
            int py = bk / SSC, px = bk - py * SSC;
            // 3x3 neighborhood of peak in full 11x11 coords
            float y00 = dist[(py + 0) * SS + (px + 0)], y01 = dist[(py + 0) * SS + (px + 1)], y02 = dist[(py + 0) * SS + (px + 2)];
            float y10 = dist[(py + 1) * SS + (px + 0)], y11 = dist[(py + 1) * SS + (px + 1)], y12 = dist[(py + 1) * SS + (px + 2)];
            float y20 = dist[(py + 2) * SS + (px + 0)], y21 = dist[(py + 2) * SS + (px + 1)], y22 = dist[(py + 2) * SS + (px + 2)];

            float a11 = (y00 - 2.0f * y01 + y02 + 2.0f * y10 - 4.0f * y11 + 2.0f * y12 + y20 - 2.0f * y21 + y22) * 0.25f;
            a11 = fmaxf(a11, 0.0f);
            float a22 = (y00 + 2.0f * y01 + y02 - 2.0f * y10 - 4.0f * y11 - 2.0f * y12 + y20 + 2.0f * y21 + y22) * 0.25f;
            a22 = fmaxf(a22, 0.0f);
            float a12 = (y00 - y02 - y20 + y22) * 0.25f;
            float b1  = (-y00 + y02 - 2.0f * y10 + 2.0f * y12 - y20 + y22) * 0.125f;
            float b2  = (-y00 - 2.0f * y01 - y02 + y20 + 2.0f * y21 + y22) * 0.125f;

            float det  = a11 * a22 - a12 * a12;
            float a12z = (det < 0.0f) ? 0.0f : a12;
            float mu_x = -(a22 * b1 - a12z * b2) / det;   // inf/nan when det==0 -> filtered below
            float mu_y = -(a11 * b2 - a12z * b1) / det;
            float mu_len = sqrtf(mu_x * mu_x + mu_y * mu_y);
            float addx = (mu_len < 1.0f) ? mu_x : 0.0f;   // NaN compares false (matches jnp.where)
            float addy = (mu_len < 1.0f) ? mu_y : 0.0f;

            float* o = outOff + ((size_t)(b * NTH + ty) * NTW + tx) * 2;
            o[0] = initf[0] + (float)(py - 4) + addy;
            o[1] = initf[1] + (float)(px - 4) + addx;
            if (LAST) outMinDist[(size_t)(b * NTH + ty) * NTW + tx] = bv;
        }
        __syncthreads();
    }
}

__global__ void __launch_bounds__(NTHR, 4)
fused_align_kernel(const float* __restrict__ src, const float* __restrict__ dst,
                   float* __restrict__ out, float* __restrict__ ws) {
    __shared__ float win[WIN * WIN];
    __shared__ float stile[TSZ * TSZ];
    __shared__ float dist[SS * SS];
    __shared__ float initf[2];
    __shared__ int   ioff[2];

    cg::grid_group grid = cg::this_grid();
    const int bid  = blockIdx.x;
    const int t    = threadIdx.x;
    const int gtid = bid * NTHR + t;
    const int nthr = NBLK * NTHR;

    // Workspace layout (floats)
    float* off3  = ws;               // 4*4*4*2
    float* off2  = ws + 128;         // 4*8*8*2
    float* off1  = ws + 640;         // 4*16*16*2
    float* off0  = ws + 2688;        // 4*32*32*2
    float* mind0 = ws + 10880;       // 4*32*32
    float* sL1 = ws + 16384;         // 4*256*256
    float* sL2 = sL1 + 262144;       // 4*128*128
    float* sL3 = sL2 + 65536;        // 4*64*64
    float* dL1 = sL3 + 16384;
    float* dL2 = dL1 + 262144;
    float* dL3 = dL2 + 65536;

    pyr_phase<512, 512>(src, dst, sL1, dL1, gtid, nthr);
    grid.sync();
    pyr_phase<256, 256>(sL1, dL1, sL2, dL2, gtid, nthr);
    grid.sync();
    pyr_phase<128, 128>(sL2, dL2, sL3, dL3, gtid, nthr);
    grid.sync();

    step_phase< 64,  64,  4,  4, true,  false>(sL3, dL3, nullptr, off3, nullptr, win, stile, dist, initf, ioff, bid, NBLK, t);
    grid.sync();
    step_phase<128, 128,  8,  8, false, false>(sL2, dL2, off3, off2, nullptr, win, stile, dist, initf, ioff, bid, NBLK, t);
    grid.sync();
    step_phase<256, 256, 16, 16, false, false>(sL1, dL1, off2, off1, nullptr, win, stile, dist, initf, ioff, bid, NBLK, t);
    grid.sync();
    step_phase<512, 512, 32, 32, false, true >(src, dst, off1, off0, mind0, win, stile, dist, initf, ioff, bid, NBLK, t);
    grid.sync();

    // Expand (4,32,32,{2,1}) to pixel resolution, concat-flat.
    const int NPIX = NB * 512 * 512;
    for (int idx = gtid; idx < NPIX; idx += nthr) {
        int x = idx & 511;
        int y = (idx >> 9) & 511;
        int b = idx >> 18;
        int ti = (b * 32 + (y >> 4)) * 32 + (x >> 4);
        float2 o = ((const float2*)off0)[ti];
        ((float2*)out)[idx] = o;
        out[(size_t)NPIX * 2 + idx] = mind0[ti];
    }
}

extern "C" void kernel_launch(void* const* d_in, const int* in_sizes, int n_in,
                              void* d_out, int out_size, void* d_ws, size_t ws_size,
                              hipStream_t stream) {
    const float* src = (const float*)d_in[0];   // (4,1,512,512)
    const float* dst = (const float*)d_in[1];   // (4,1,512,512)
    float* out = (float*)d_out;                  // offsets (NPIX*2) ++ dist (NPIX)
    float* ws  = (float*)d_ws;

    void* args[] = { (void*)&src, (void*)&dst, (void*)&out, (void*)&ws };
    hipLaunchCooperativeKernel((const void*)fused_align_kernel,
                               dim3(NBLK), dim3(NTHR), args, 0, stream);
}

// Round 3
// 114.749 us; speedup vs baseline: 7.5887x; 7.5887x over previous
//
#include <hip/hip_runtime.h>

// HDR+ align, 2-kernel version.
// K1: full gaussian pyramid hierarchically in LDS (one launch).
// K2: all 4 block-matching levels as a per-block quadtree walk + fused expand.
// Constants: T=16, SR=4, PADD=1, SS=11, SSC=9, WIN=26, SW=0.1, GR=2, batch 4, 512x512.

#define NB 4

// Composite 1D tap of (normalized gaussian sigma=1 r=2) followed by avg-pool-2.
// constexpr so products fold to literals at compile time.
constexpr float H6[6] = {
    0.027244342f, 0.149345013f, 0.323410645f,
    0.323410645f, 0.149345013f, 0.027244342f
};

// ---------------------------------------------------------------------------
// K1: pyramid. One block = 8x8 region of L3 of one image (grid 8x8x8).
// LDS overlay plan (floats):
//   [0..9899]      patch  99 rows stride 100   (phase P0..P1)
//   [9900..14651]  tmpH   99 rows stride 48    (P1..P2)
//   [0..2255]      l1     47 rows stride 48    (P2..)   overlays dead patch
//   [2256..3383]   tmpB   47 rows stride 24    (P3b..)
//   [9900..10403]  l2     21 rows stride 24    (P4..)   overlays dead tmpH
//   [3384..3551]   tmp3   21 rows stride 8     (P5b..)
// ---------------------------------------------------------------------------
__global__ void __launch_bounds__(256, 2)
pyramid_kernel(const float* __restrict__ src, const float* __restrict__ dst,
               float* __restrict__ ws) {
    __shared__ float smem[14652];
    float* patch = smem;          // stride 100
    float* tmpH  = smem + 9900;   // stride 48
    float* l1    = smem;          // stride 48
    float* tmpB  = smem + 2256;   // stride 24
    float* l2    = smem + 9900;   // stride 24
    float* tmp3  = smem + 3384;   // stride 8

    float* sL1 = ws;
    float* dL1 = sL1 + 4 * 65536;
    float* sL2 = dL1 + 4 * 65536;
    float* dL2 = sL2 + 4 * 16384;
    float* sL3 = dL2 + 4 * 16384;
    float* dL3 = sL3 + 4 * 4096;

    const int bx = blockIdx.x, by = blockIdx.y, z = blockIdx.z;
    const int t = threadIdx.x;

    const float* in = (z < 4) ? (src + (size_t)z * 262144) : (dst + (size_t)(z - 4) * 262144);
    float* outL1 = ((z < 4) ? sL1 : dL1) + (size_t)(z & 3) * 65536;
    float* outL2 = ((z < 4) ? sL2 : dL2) + (size_t)(z & 3) * 16384;
    float* outL3 = ((z < 4) ? sL3 : dL3) + (size_t)(z & 3) * 4096;

    // P0: load 99x99 L0 patch at offset (by*64-14, bx*64-14), zero OOB (zero-pad conv).
    {
        const int oy = by * 64 - 14, ox = bx * 64 - 14;
        for (int idx = t; idx < 99 * 99; idx += 256) {
            int r = idx / 99, c = idx - r * 99;
            int gy = oy + r, gx = ox + c;
            float v = 0.0f;
            if (gy >= 0 && gy < 512 && gx >= 0 && gx < 512) v = in[gy * 512 + gx];
            patch[r * 100 + c] = v;
        }
    }
    __syncthreads();
    // P1: horizontal pass -> tmpH[r<99][v<47]
    for (int idx = t; idx < 99 * 47; idx += 256) {
        int r = idx / 47, v = idx - r * 47;
        const float* p = &patch[r * 100 + 2 * v];
        float a = 0.f;
        #pragma unroll
        for (int b = 0; b < 6; ++b) a = fmaf(H6[b], p[b], a);
        tmpH[r * 48 + v] = a;
    }
    __syncthreads();
    // P2: vertical pass -> l1[u<47][v<47], zero if L1 coord OOB (per-level zero-pad).
    {
        const int oy = by * 32 - 6, ox = bx * 32 - 6;
        for (int idx = t; idx < 47 * 47; idx += 256) {
            int u = idx / 47, v = idx - u * 47;
            float a = 0.f;
            int y1 = oy + u, x1 = ox + v;
            if (y1 >= 0 && y1 < 256 && x1 >= 0 && x1 < 256) {
                #pragma unroll
                for (int b = 0; b < 6; ++b) a = fmaf(H6[b], tmpH[(2 * u + b) * 48 + v], a);
            }
            l1[u * 48 + v] = a;
        }
    }
    __syncthreads();
    // P3: write canonical L1 32x32 + horizontal pass for L2 -> tmpB[r<47][v<21]
    for (int idx = t; idx < 1024; idx += 256) {
        int u = idx >> 5, v = idx & 31;
        outL1[(by * 32 + u) * 256 + bx * 32 + v] = l1[(6 + u) * 48 + 6 + v];
    }
    for (int idx = t; idx < 47 * 21; idx += 256) {
        int r = idx / 21, v = idx - r * 21;
        const float* p = &l1[r * 48 + 2 * v];
        float a = 0.f;
        #pragma unroll
        for (int b = 0; b < 6; ++b) a = fmaf(H6[b], p[b], a);
        tmpB[r * 24 + v] = a;
    }
    __syncthreads();
    // P4: vertical -> l2[u<21][v<21], zero if L2 coord OOB.
    {
        const int oy = by * 16 - 2, ox = bx * 16 - 2;
        for (int idx = t; idx < 21 * 21; idx += 256) {
            int u = idx / 21, v = idx - u * 21;
            float a = 0.f;
            int y2 = oy + u, x2 = ox + v;
            if (y2 >= 0 && y2 < 128 && x2 >= 0 && x2 < 128) {
                #pragma unroll
                for (int b = 0; b < 6; ++b) a = fmaf(H6[b], tmpB[(2 * u + b) * 24 + v], a);
            }
            l2[u * 24 + v] = a;
        }
    }
    __syncthreads();
    // P5: write canonical L2 16x16 + horizontal for L3 -> tmp3[r<21][v<8]
    for (int idx = t; idx < 256; idx += 256) {
        int u = idx >> 4, v = idx & 15;
        outL2[(by * 16 + u) * 128 + bx * 16 + v] = l2[(2 + u) * 24 + 2 + v];
    }
    for (int idx = t; idx < 21 * 8; idx += 256) {
        int r = idx >> 3, v = idx & 7;
        const float* p = &l2[r * 24 + 2 * v];
        float a = 0.f;
        #pragma unroll
        for (int b = 0; b < 6; ++b) a = fmaf(H6[b], p[b], a);
        tmp3[r * 8 + v] = a;
    }
    __syncthreads();
    // P6: vertical -> L3 8x8 (always in-bounds), write global.
    if (t < 64) {
        int u = t >> 3, v = t & 7;
        float a = 0.f;
        #pragma unroll
        for (int b = 0; b < 6; ++b) a = fmaf(H6[b], tmp3[(2 * u + b) * 8 + v], a);
        outL3[(by * 8 + u) * 64 + bx * 8 + v] = a;
    }
}

// ---------------------------------------------------------------------------
// K2: quadtree block matching + expand. One block per S1 tile (1024 blocks,
// 256 threads = 2 slots x 128). Rounds: S3, S2, S1 (slot0), then 4 S0 children
// (2 rounds x 2 slots) with the pixel-expand fused after each S0 round.
// SSD scheme: lane=(dy,ig) keeps a window row in registers (7x ds_read_b128),
// computes all 11 dx candidates from registers; 8x less LDS traffic than
// candidate-per-lane.
// ---------------------------------------------------------------------------
__global__ void __launch_bounds__(256, 4)
step_chain_kernel(const float* __restrict__ src, const float* __restrict__ dst,
                  const float* __restrict__ ws, float* __restrict__ out) {
    __shared__ float winS[2][26 * 28];   // padded rows, stride 28 (112B, 16B-mult)
    __shared__ float stS[2][256];
    __shared__ float distS[2][128];      // 121 used
    __shared__ float offLv[4][2];        // per-level block-local offsets
    __shared__ float resY[2], resX[2], resD[2];

    const float* sL1 = ws;
    const float* dL1 = sL1 + 4 * 65536;
    const float* sL2 = dL1 + 4 * 65536;
    const float* dL2 = sL2 + 4 * 16384;
    const float* sL3 = dL2 + 4 * 16384;
    const float* dL3 = sL3 + 4 * 4096;

    const int gid = blockIdx.x;          // 0..1023
    const int b   = gid >> 8;
    const int ty1 = (gid >> 4) & 15;
    const int tx1 = gid & 15;
    const int t    = threadIdx.x;
    const int slot = t >> 7;
    const int s_t  = t & 127;
    const int NPIX = NB * 512 * 512;

    float* win  = winS[slot];
    float* st   = stS[slot];
    float* dist = distS[slot];

    #pragma unroll 1
    for (int round = 0; round < 5; ++round) {
        int lvl, ty, tx; bool act, hasPar;
        const float* simg; const float* dimg; int H;
        switch (round) {
            case 0: lvl = 3; ty = ty1 >> 2; tx = tx1 >> 2; act = (slot == 0); hasPar = false; break;
            case 1: lvl = 2; ty = ty1 >> 1; tx = tx1 >> 1; act = (slot == 0); hasPar = true;  break;
            case 2: lvl = 1; ty = ty1;      tx = tx1;      act = (slot == 0); hasPar = true;  break;
            case 3: lvl = 0; ty = 2 * ty1;     tx = 2 * tx1 + slot; act = true; hasPar = true; break;
            default:lvl = 0; ty = 2 * ty1 + 1; tx = 2 * tx1 + slot; act = true; hasPar = true; break;
        }
        switch (lvl) {
            case 0: simg = src + (size_t)b * 262144; dimg = dst + (size_t)b * 262144; H = 512; break;
            case 1: simg = sL1 + (size_t)b * 65536;  dimg = dL1 + (size_t)b * 65536;  H = 256; break;
            case 2: simg = sL2 + (size_t)b * 16384;  dimg = dL2 + (size_t)b * 16384;  H = 128; break;
            default:simg = sL3 + (size_t)b * 4096;   dimg = dL3 + (size_t)b * 4096;   H = 64;  break;
        }

        // Inherit (computed redundantly by every thread; offLv synced last round).
        float dyf = 0.f, dxf = 0.f;
        if (hasPar) {
            float poy = offLv[lvl + 1][0], pox = offLv[lvl + 1][1];
            float iy = (float)(ty * 16), ix = (float)(tx * 16);
            dyf = rintf(fminf(fmaxf(2.f * poy + iy, 0.f), (float)(H - 16)) - iy);
            dxf = rintf(fminf(fmaxf(2.f * pox + ix, 0.f), (float)(H - 16)) - ix);
        }
        const int ioy = (int)dyf, iox = (int)dxf;

        if (act) {
            const int y0 = ty * 16 + ioy - 5;
            const int x0 = tx * 16 + iox - 5;
            for (int idx = s_t; idx < 26 * 26; idx += 128) {
                int r = idx / 26, c = idx - r * 26;
                int gy = min(max(y0 + r, 0), H - 1);
                int gx = min(max(x0 + c, 0), H - 1);
                win[r * 28 + c] = dimg[gy * H + gx];
            }
            if (s_t < 64) {
                int r = s_t >> 2, q = s_t & 3;
                const float4* srow = (const float4*)(simg + (size_t)(ty * 16 + r) * H + tx * 16);
                ((float4*)&st[r * 16])[q] = srow[q];
            }
        }
        __syncthreads();

        // SSD: lane = (dy = s_t>>3, ig = s_t&7), rows i = ig*2, ig*2+1.
        if (act) {
            const int dy = s_t >> 3;
            const int dyc = min(dy, 10);
            float acc[11];
            #pragma unroll
            for (int q = 0; q < 11; ++q) acc[q] = 0.f;
            #pragma unroll
            for (int rr = 0; rr < 2; ++rr) {
                const int i = (s_t & 7) * 2 + rr;
                float w[28], s[16];
                const float4* wp = (const float4*)&win[(dyc + i) * 28];
                #pragma unroll
                for (int q = 0; q < 7; ++q) {
                    float4 v = wp[q];
                    w[4 * q] = v.x; w[4 * q + 1] = v.y; w[4 * q + 2] = v.z; w[4 * q + 3] = v.w;
                }
                const float4* sp = (const float4*)&st[i * 16];
                #pragma unroll
                for (int q = 0; q < 4; ++q) {
                    float4 v = sp[q];
                    s[4 * q] = v.x; s[4 * q + 1] = v.y; s[4 * q + 2] = v.z; s[4 * q + 3] = v.w;
                }
                #pragma unroll
                for (int dx = 0; dx < 11; ++dx) {
                    #pragma unroll
                    for (int j = 0; j < 16; ++j) {
                        float d = w[dx + j] - s[j];
                        acc[dx] = fmaf(d, d, acc[dx]);
                    }
                }
            }
            // reduce over ig (groups of 8 consecutive lanes, within-wave)
            #pragma unroll
            for (int m = 1; m <= 4; m <<= 1) {
                #pragma unroll
                for (int dx = 0; dx < 11; ++dx) acc[dx] += __shfl_xor(acc[dx], m);
            }
            if ((s_t & 7) == 0 && dy < 11) {
                float ay = (float)(dy - 5) * (1.f / 11.f);
                #pragma unroll
                for (int dx = 0; dx < 11; ++dx) {
                    float ax = (float)(dx - 5) * (1.f / 11.f);
                    dist[dy * 11 + dx] = acc[dx] * (1.f / 256.f) + 0.1f * (ay * ay + ax * ax);
                }
            }
        }
        __syncthreads();

        // Argmin over central 9x9 (first occurrence) + subpixel, per slot.
        if (act && s_t < 64) {
            float bv = 3e38f; int bk = 1 << 30;
            {
                int k = s_t;
                if (k < 81) {
                    int py = k / 9, px = k - (k / 9) * 9;
                    bv = dist[(py + 1) * 11 + (px + 1)]; bk = k;
                }
                k = s_t + 64;
                if (k < 81) {
                    int py = k / 9, px = k - (k / 9) * 9;
                    float d = dist[(py + 1) * 11 + (px + 1)];
                    if (d < bv || (d == bv && k < bk)) { bv = d; bk = k; }
                }
            }
            #pragma unroll
            for (int sft = 32; sft > 0; sft >>= 1) {
                float ov = __shfl_down(bv, sft);
                int   ok = __shfl_down(bk, sft);
                if (ov < bv || (ov == bv && ok < bk)) { bv = ov; bk = ok; }
            }
            if (s_t == 0) {
                int py = bk / 9, px = bk - py * 9;
                float y00 = dist[(py + 0) * 11 + (px + 0)], y01 = dist[(py + 0) * 11 + (px + 1)], y02 = dist[(py + 0) * 11 + (px + 2)];
                float y10 = dist[(py + 1) * 11 + (px + 0)],                                       y12 = dist[(py + 1) * 11 + (px + 2)];
                float y11 = dist[(py + 1) * 11 + (px + 1)];
                float y20 = dist[(py + 2) * 11 + (px + 0)], y21 = dist[(py + 2) * 11 + (px + 1)], y22 = dist[(py + 2) * 11 + (px + 2)];

                float a11 = (y00 - 2.f * y01 + y02 + 2.f * y10 - 4.f * y11 + 2.f * y12 + y20 - 2.f * y21 + y22) * 0.25f;
                a11 = fmaxf(a11, 0.f);
                float a22 = (y00 + 2.f * y01 + y02 - 2.f * y10 - 4.f * y11 - 2.f * y12 + y20 + 2.f * y21 + y22) * 0.25f;
                a22 = fmaxf(a22, 0.f);
                float a12 = (y00 - y02 - y20 + y22) * 0.25f;
                float b1  = (-y00 + y02 - 2.f * y10 + 2.f * y12 - y20 + y22) * 0.125f;
                float b2  = (-y00 - 2.f * y01 - y02 + y20 + 2.f * y21 + y22) * 0.125f;

                float det  = a11 * a22 - a12 * a12;
                float a12z = (det < 0.f) ? 0.f : a12;
                float mu_x = -(a22 * b1 - a12z * b2) / det;   // inf/nan filtered below
                float mu_y = -(a11 * b2 - a12z * b1) / det;
                float mu_len = sqrtf(mu_x * mu_x + mu_y * mu_y);
                float addx = (mu_len < 1.f) ? mu_x : 0.f;     // NaN -> false, matches jnp.where
                float addy = (mu_len < 1.f) ? mu_y : 0.f;

                float oy = dyf + (float)(py - 4) + addy;
                float ox = dxf + (float)(px - 4) + addx;
                if (lvl > 0) { offLv[lvl][0] = oy; offLv[lvl][1] = ox; }
                resY[slot] = oy; resX[slot] = ox; resD[slot] = bv;
            }
        }
        __syncthreads();

        // Fused expand for level-0 rounds: each slot writes its 16x16 pixel tile.
        if (lvl == 0) {
            float2 o; o.x = resY[slot]; o.y = resX[slot];
            float2 dd; dd.x = resD[slot]; dd.y = resD[slot];
            int r = s_t >> 3, c = (s_t & 7) * 2;
            int py = ty * 16 + r, px = tx * 16 + c;
            size_t pi = ((size_t)(b * 512 + py)) * 512 + px;
            ((float2*)out)[pi]     = o;
            ((float2*)out)[pi + 1] = o;
            *(float2*)(out + (size_t)NPIX * 2 + pi) = dd;
            __syncthreads();
        }
    }
}

extern "C" void kernel_launch(void* const* d_in, const int* in_sizes, int n_in,
                              void* d_out, int out_size, void* d_ws, size_t ws_size,
                              hipStream_t stream) {
    const float* src = (const float*)d_in[0];   // (4,1,512,512)
    const float* dst = (const float*)d_in[1];   // (4,1,512,512)
    float* out = (float*)d_out;                  // offsets (NPIX*2) ++ dist (NPIX)
    float* ws  = (float*)d_ws;                   // pyramid levels, 2.75 MB

    hipLaunchKernelGGL(pyramid_kernel, dim3(8, 8, 8), dim3(256), 0, stream, src, dst, ws);
    hipLaunchKernelGGL(step_chain_kernel, dim3(1024), dim3(256), 0, stream, src, dst, ws, out);
}

// Round 4
// 112.122 us; speedup vs baseline: 7.7665x; 1.0234x over previous
//
#include <hip/hip_runtime.h>

// HDR+ align, 2-kernel version, round 4.
// K1: pyramid, 4x4-L3 tiles (22KB LDS, 2048 blocks) hierarchically in LDS.
// K2: quadtree block matching: 2 barriers/round, register-carried offsets,
//     redundant per-lane argmin/subpixel, 1-row/lane SSD (no spills).
// Constants: T=16, SR=4, PADD=1, SS=11, SSC=9, WIN=26, SW=0.1, GR=2, batch 4, 512x512.

#define NB 4
#define NPIX (NB * 512 * 512)

// Composite 1D tap of (normalized gaussian sigma=1 r=2) followed by avg-pool-2.
constexpr float H6[6] = {
    0.027244342f, 0.149345013f, 0.323410645f,
    0.323410645f, 0.149345013f, 0.027244342f
};

// ---------------------------------------------------------------------------
// K1: pyramid. One block = 4x4 region of L3 (covers 32x32 L0). Grid (16,16,8).
// LDS overlay (floats): patch[0..3839] s64, tmpH1[3840..5519] s28,
// l1[0..783] s28 (overlays dead patch), tmpH2[784..1119] s12,
// l2[1120..1263] s12, tmpH3[1264..1311] s4.  Total 5520 fl = 22.1 KB.
// ---------------------------------------------------------------------------
__global__ void __launch_bounds__(256, 4)
pyramid_kernel(const float* __restrict__ src, const float* __restrict__ dst,
               float* __restrict__ ws) {
    __shared__ float smem[5520];
    float* patch = smem;            // 60 rows, stride 64
    float* tmpH1 = smem + 3840;     // 60 rows, stride 28
    float* l1    = smem;            // 28 rows, stride 28
    float* tmpH2 = smem + 784;      // 28 rows, stride 12
    float* l2    = smem + 1120;     // 12 rows, stride 12
    float* tmpH3 = smem + 1264;     // 12 rows, stride 4

    float* sL1 = ws;
    float* dL1 = sL1 + 4 * 65536;
    float* sL2 = dL1 + 4 * 65536;
    float* dL2 = sL2 + 4 * 16384;
    float* sL3 = dL2 + 4 * 16384;
    float* dL3 = sL3 + 4 * 4096;

    const int bx = blockIdx.x, by = blockIdx.y, z = blockIdx.z;
    const int t = threadIdx.x;
    const float* in = (z < 4) ? (src + (size_t)z * 262144) : (dst + (size_t)(z - 4) * 262144);
    float* oL1 = ((z < 4) ? sL1 : dL1) + (size_t)(z & 3) * 65536;
    float* oL2 = ((z < 4) ? sL2 : dL2) + (size_t)(z & 3) * 16384;
    float* oL3 = ((z < 4) ? sL3 : dL3) + (size_t)(z & 3) * 4096;

    // P0: 60x60 L0 patch at (by*32-14, bx*32-14), zero OOB (conv zero-pad).
    {
        const int oy = by * 32 - 14, ox = bx * 32 - 14;
        for (int idx = t; idx < 3600; idx += 256) {
            int r = idx / 60, c = idx - r * 60;
            int gy = oy + r, gx = ox + c;
            float v = 0.f;
            if ((unsigned)gy < 512u && (unsigned)gx < 512u) v = in[gy * 512 + gx];
            patch[r * 64 + c] = v;
        }
    }
    __syncthreads();
    // P1: horizontal -> tmpH1[60][28]
    for (int idx = t; idx < 1680; idx += 256) {
        int r = idx / 28, v = idx - r * 28;
        const float* p = &patch[r * 64 + 2 * v];
        float a = 0.f;
        #pragma unroll
        for (int bq = 0; bq < 6; ++bq) a = fmaf(H6[bq], p[bq], a);
        tmpH1[r * 28 + v] = a;
    }
    __syncthreads();
    // P2: vertical -> l1[28][28]; zero if L1 coord OOB (per-level zero-pad).
    {
        const int oy = by * 16 - 6, ox = bx * 16 - 6;
        for (int idx = t; idx < 784; idx += 256) {
            int u = idx / 28, v = idx - u * 28;
            float a = 0.f;
            int y1 = oy + u, x1 = ox + v;
            if ((unsigned)y1 < 256u && (unsigned)x1 < 256u) {
                #pragma unroll
                for (int bq = 0; bq < 6; ++bq) a = fmaf(H6[bq], tmpH1[(2 * u + bq) * 28 + v], a);
            }
            l1[u * 28 + v] = a;
        }
    }
    __syncthreads();
    // P3: write canonical L1 16x16 + horizontal -> tmpH2[28][12]
    {
        int u = t >> 4, v = t & 15;
        oL1[(by * 16 + u) * 256 + bx * 16 + v] = l1[(6 + u) * 28 + 6 + v];
    }
    for (int idx = t; idx < 336; idx += 256) {
        int r = idx / 12, v = idx - r * 12;
        const float* p = &l1[r * 28 + 2 * v];
        float a = 0.f;
        #pragma unroll
        for (int bq = 0; bq < 6; ++bq) a = fmaf(H6[bq], p[bq], a);
        tmpH2[r * 12 + v] = a;
    }
    __syncthreads();
    // P4: vertical -> l2[12][12]; zero if L2 coord OOB.
    {
        const int oy = by * 8 - 2, ox = bx * 8 - 2;
        if (t < 144) {
            int u = t / 12, v = t - u * 12;
            float a = 0.f;
            int y2 = oy + u, x2 = ox + v;
            if ((unsigned)y2 < 128u && (unsigned)x2 < 128u) {
                #pragma unroll
                for (int bq = 0; bq < 6; ++bq) a = fmaf(H6[bq], tmpH2[(2 * u + bq) * 12 + v], a);
            }
            l2[u * 12 + v] = a;
        }
    }
    __syncthreads();
    // P5: write canonical L2 8x8 + horizontal -> tmpH3[12][4]
    if (t < 64) {
        int u = t >> 3, v = t & 7;
        oL2[(by * 8 + u) * 128 + bx * 8 + v] = l2[(2 + u) * 12 + 2 + v];
    } else if (t < 112) {
        int idx = t - 64;
        int r = idx >> 2, v = idx & 3;
        const float* p = &l2[r * 12 + 2 * v];
        float a = 0.f;
        #pragma unroll
        for (int bq = 0; bq < 6; ++bq) a = fmaf(H6[bq], p[bq], a);
        tmpH3[r * 4 + v] = a;
    }
    __syncthreads();
    // P6: vertical -> L3 4x4, write global.
    if (t < 16) {
        int u = t >> 2, v = t & 3;
        float a = 0.f;
        #pragma unroll
        for (int bq = 0; bq < 6; ++bq) a = fmaf(H6[bq], tmpH3[(2 * u + bq) * 4 + v], a);
        oL3[(by * 4 + u) * 64 + bx * 4 + v] = a;
    }
}

// ---------------------------------------------------------------------------
// K2 helper: one block-matching level. FULL=true: all 256 threads, 1 row/lane.
// FULL=false: a 128-thread slot, 2 rows/lane (sequential). Exactly 2 barriers.
// Result (oy, ox, od) is computed redundantly by EVERY lane (identical fp ops
// on identical LDS data -> bitwise identical) so offsets live in registers.
// ---------------------------------------------------------------------------
template<bool FULL>
__device__ __forceinline__ void do_level(const float* __restrict__ simg,
                                         const float* __restrict__ dimg, int H,
                                         int ty, int tx, float pary, float parx, bool first,
                                         float* win, float* st, float* dist, int lt,
                                         float& roy, float& rox, float& rod) {
    constexpr int NL = FULL ? 256 : 128;

    float dyf = 0.f, dxf = 0.f;
    if (!first) {
        float iy = (float)(ty * 16), ix = (float)(tx * 16);
        // _inherit: round(clip(2*par + i, 0, H-16) - i), half-to-even (rintf).
        dyf = rintf(fminf(fmaxf(2.f * pary + iy, 0.f), (float)(H - 16)) - iy);
        dxf = rintf(fminf(fmaxf(2.f * parx + ix, 0.f), (float)(H - 16)) - ix);
    }
    const int ioy = (int)dyf, iox = (int)dxf;
    const int y0 = ty * 16 + ioy - 5;
    const int x0 = tx * 16 + iox - 5;

    for (int idx = lt; idx < 676; idx += NL) {
        int r = idx / 26, c = idx - r * 26;
        int gy = min(max(y0 + r, 0), H - 1);
        int gx = min(max(x0 + c, 0), H - 1);
        win[r * 28 + c] = dimg[gy * H + gx];
    }
    if (lt < 64) {
        int r = lt >> 2, q = lt & 3;
        const float4* srow = (const float4*)(simg + (size_t)(ty * 16 + r) * H + tx * 16);
        ((float4*)&st[r * 16])[q] = srow[q];
    }
    __syncthreads();   // B1

    const int dy = FULL ? (lt >> 4) : (lt >> 3);
    if (dy < 11) {
        float acc[11];
        #pragma unroll
        for (int q = 0; q < 11; ++q) acc[q] = 0.f;
        constexpr int ROWS = FULL ? 1 : 2;
        #pragma unroll
        for (int rr = 0; rr < ROWS; ++rr) {
            const int i = FULL ? (lt & 15) : ((lt & 7) * 2 + rr);
            float w[28], s[16];
            const float4* wp = (const float4*)&win[(dy + i) * 28];
            #pragma unroll
            for (int q = 0; q < 7; ++q) ((float4*)w)[q] = wp[q];
            const float4* sp = (const float4*)&st[i * 16];
            #pragma unroll
            for (int q = 0; q < 4; ++q) ((float4*)s)[q] = sp[q];
            #pragma unroll
            for (int dx = 0; dx < 11; ++dx) {
                #pragma unroll
                for (int j = 0; j < 16; ++j) {
                    float d = w[dx + j] - s[j];
                    acc[dx] = fmaf(d, d, acc[dx]);
                }
            }
        }
        // reduce over row groups (within-wave shfl_xor)
        constexpr int MMAX = FULL ? 8 : 4;
        #pragma unroll
        for (int m = 1; m <= MMAX; m <<= 1) {
            #pragma unroll
            for (int dx = 0; dx < 11; ++dx) acc[dx] += __shfl_xor(acc[dx], m);
        }
        const bool leader = FULL ? ((lt & 15) == 0) : ((lt & 7) == 0);
        if (leader) {
            float ay = (float)(dy - 5) * (1.f / 11.f);
            #pragma unroll
            for (int dx = 0; dx < 11; ++dx) {
                float ax = (float)(dx - 5) * (1.f / 11.f);
                dist[dy * 11 + dx] = acc[dx] * (1.f / 256.f) + 0.1f * (ay * ay + ax * ax);
            }
        }
    }
    __syncthreads();   // B2

    // Redundant per-lane argmin over central 9x9 (first occurrence on ties).
    const int l = lt & 63;
    float bv; int bk;
    {
        int k = l;                                    // 0..63 < 81 always
        int py = k / 9, px = k - (k / 9) * 9;
        bv = dist[(py + 1) * 11 + (px + 1)]; bk = k;
        k = l + 64;
        if (k < 81) {
            py = k / 9; px = k - (k / 9) * 9;
            float d = dist[(py + 1) * 11 + (px + 1)];
            if (d < bv) { bv = d; bk = k; }           // strict: tie keeps smaller k
        }
    }
    #pragma unroll
    for (int m = 1; m <= 32; m <<= 1) {
        float ov = __shfl_xor(bv, m);
        int   ok = __shfl_xor(bk, m);
        if (ov < bv || (ov == bv && ok < bk)) { bv = ov; bk = ok; }
    }
    // Redundant per-lane subpixel refine (broadcast LDS reads).
    {
        int py = bk / 9, px = bk - (bk / 9) * 9;
        float y00 = dist[(py + 0) * 11 + (px + 0)], y01 = dist[(py + 0) * 11 + (px + 1)], y02 = dist[(py + 0) * 11 + (px + 2)];
        float y10 = dist[(py + 1) * 11 + (px + 0)], y11 = dist[(py + 1) * 11 + (px + 1)], y12 = dist[(py + 1) * 11 + (px + 2)];
        float y20 = dist[(py + 2) * 11 + (px + 0)], y21 = dist[(py + 2) * 11 + (px + 1)], y22 = dist[(py + 2) * 11 + (px + 2)];

        float a11 = (y00 - 2.f * y01 + y02 + 2.f * y10 - 4.f * y11 + 2.f * y12 + y20 - 2.f * y21 + y22) * 0.25f;
        a11 = fmaxf(a11, 0.f);
        float a22 = (y00 + 2.f * y01 + y02 - 2.f * y10 - 4.f * y11 - 2.f * y12 + y20 + 2.f * y21 + y22) * 0.25f;
        a22 = fmaxf(a22, 0.f);
        float a12 = (y00 - y02 - y20 + y22) * 0.25f;
        float b1  = (-y00 + y02 - 2.f * y10 + 2.f * y12 - y20 + y22) * 0.125f;
        float b2  = (-y00 - 2.f * y01 - y02 + y20 + 2.f * y21 + y22) * 0.125f;

        float det  = a11 * a22 - a12 * a12;
        float a12z = (det < 0.f) ? 0.f : a12;
        float mu_x = -(a22 * b1 - a12z * b2) / det;   // inf/nan when det==0 -> filtered
        float mu_y = -(a11 * b2 - a12z * b1) / det;
        float mu_len = sqrtf(mu_x * mu_x + mu_y * mu_y);
        float addx = (mu_len < 1.f) ? mu_x : 0.f;     // NaN -> false, matches jnp.where
        float addy = (mu_len < 1.f) ? mu_y : 0.f;

        roy = dyf + (float)(py - 4) + addy;
        rox = dxf + (float)(px - 4) + addx;
        rod = bv;
    }
}

// ---------------------------------------------------------------------------
// K2: one block per S1 tile (1024 blocks, 256 thr). Rounds: S3,S2,S1 full-width,
// then 2 rounds of 2 S0 children (128-thr slots) with fused pixel expand.
// ---------------------------------------------------------------------------
__global__ void __launch_bounds__(256, 4)
step_chain_kernel(const float* __restrict__ src, const float* __restrict__ dst,
                  const float* __restrict__ ws, float* __restrict__ out) {
    __shared__ float winS[2][26 * 28];
    __shared__ float stS[2][256];
    __shared__ float distS[2][128];

    const float* sL1 = ws;
    const float* dL1 = sL1 + 4 * 65536;
    const float* sL2 = dL1 + 4 * 65536;
    const float* dL2 = sL2 + 4 * 16384;
    const float* sL3 = dL2 + 4 * 16384;
    const float* dL3 = sL3 + 4 * 4096;

    const int gid = blockIdx.x;
    const int b   = gid >> 8;
    const int ty1 = (gid >> 4) & 15;
    const int tx1 = gid & 15;
    const int t    = threadIdx.x;
    const int slot = t >> 7;
    const int s_t  = t & 127;

    const float* s0 = src + (size_t)b * 262144; const float* d0 = dst + (size_t)b * 262144;
    const float* s1 = sL1 + (size_t)b * 65536;  const float* d1 = dL1 + (size_t)b * 65536;
    const float* s2 = sL2 + (size_t)b * 16384;  const float* d2 = dL2 + (size_t)b * 16384;
    const float* s3 = sL3 + (size_t)b * 4096;   const float* d3 = dL3 + (size_t)b * 4096;

    float oy, ox, od;
    do_level<true>(s3, d3,  64, ty1 >> 2, tx1 >> 2, 0.f, 0.f, true,
                   winS[0], stS[0], distS[0], t, oy, ox, od);
    do_level<true>(s2, d2, 128, ty1 >> 1, tx1 >> 1, oy, ox, false,
                   winS[0], stS[0], distS[0], t, oy, ox, od);
    do_level<true>(s1, d1, 256, ty1,      tx1,      oy, ox, false,
                   winS[0], stS[0], distS[0], t, oy, ox, od);
    const float s1y = oy, s1x = ox;

    #pragma unroll
    for (int half = 0; half < 2; ++half) {
        const int ty0 = 2 * ty1 + half, tx0 = 2 * tx1 + slot;
        do_level<false>(s0, d0, 512, ty0, tx0, s1y, s1x, false,
                        winS[slot], stS[slot], distS[slot], s_t, oy, ox, od);
        // Fused expand: every lane of the slot holds identical (oy,ox,od).
        int r = s_t >> 3, c = (s_t & 7) * 2;
        int pyy = ty0 * 16 + r, pxx = tx0 * 16 + c;
        size_t pi = ((size_t)(b * 512 + pyy)) * 512 + pxx;
        float2 o; o.x = oy; o.y = ox;
        ((float2*)out)[pi]     = o;
        ((float2*)out)[pi + 1] = o;
        float2 dd; dd.x = od; dd.y = od;
        *(float2*)(out + (size_t)NPIX * 2 + pi) = dd;
    }
}

extern "C" void kernel_launch(void* const* d_in, const int* in_sizes, int n_in,
                              void* d_out, int out_size, void* d_ws, size_t ws_size,
                              hipStream_t stream) {
    const float* src = (const float*)d_in[0];   // (4,1,512,512)
    const float* dst = (const float*)d_in[1];   // (4,1,512,512)
    float* out = (float*)d_out;                  // offsets (NPIX*2) ++ dist (NPIX)
    float* ws  = (float*)d_ws;                   // pyramid levels, 2.75 MB

    hipLaunchKernelGGL(pyramid_kernel, dim3(16, 16, 8), dim3(256), 0, stream, src, dst, ws);
    hipLaunchKernelGGL(step_chain_kernel, dim3(1024), dim3(256), 0, stream, src, dst, ws, out);
}